// Round 6
// baseline (190.627 us; speedup 1.0000x reference)
//
#include <hip/hip_runtime.h>
#include <math.h>

typedef __bf16 bf16_t;
typedef __bf16 v8bf __attribute__((ext_vector_type(8)));
typedef __bf16 v4bf __attribute__((ext_vector_type(4)));
typedef float  v4f  __attribute__((ext_vector_type(4)));

#define AS1 __attribute__((address_space(1)))
#define AS3 __attribute__((address_space(3)))

// async global->LDS 16B copy; LDS dest = wave-uniform base + lane*16
static __device__ __forceinline__ void load_lds16(const bf16_t* g, bf16_t* l) {
    __builtin_amdgcn_global_load_lds((AS1 void*)const_cast<bf16_t*>(g),
                                     (AS3 void*)l, 16, 0, 0);
}
static __device__ __forceinline__ void load_lds16b(const char* g, char* l) {
    __builtin_amdgcn_global_load_lds((AS1 void*)const_cast<char*>(g),
                                     (AS3 void*)l, 16, 0, 0);
}

// sin/cos via native HW ops with explicit revolution reduction (no libcall)
static __device__ __forceinline__ void fast_sincos(float ang, float* sn, float* cs) {
    float rv = ang * 0.15915494309189535f;
    rv -= floorf(rv);
    const float a = rv * 6.283185307179586f;
    *sn = __sinf(a);
    *cs = __cosf(a);
}

// ---------------------------------------------------------------------------
// Kernel 0: fp32 -> bf16 for h + 4 weights. 8M elems, 8/thread.
// ---------------------------------------------------------------------------
__global__ __launch_bounds__(256) void cvt_fp32_bf16(
    const float* __restrict__ h,  const float* __restrict__ wq,
    const float* __restrict__ wk, const float* __restrict__ wv,
    const float* __restrict__ wo,
    bf16_t* __restrict__ hb,  bf16_t* __restrict__ wqb,
    bf16_t* __restrict__ wkb, bf16_t* __restrict__ wvb,
    bf16_t* __restrict__ wob)
{
    const size_t HM = (size_t)4 << 20;
    const size_t i8 = ((size_t)blockIdx.x * 256 + threadIdx.x) * 8;
    const float* src; bf16_t* dst; size_t off;
    if (i8 < HM) { src = h; dst = hb; off = i8; }
    else {
        const size_t r = (i8 - HM) >> 20;
        off = (i8 - HM) & (((size_t)1 << 20) - 1);
        src = (r == 0) ? wq  : (r == 1) ? wk  : (r == 2) ? wv  : wo;
        dst = (r == 0) ? wqb : (r == 1) ? wkb : (r == 2) ? wvb : wob;
    }
    const float4 a = *(const float4*)(src + off);
    const float4 b = *(const float4*)(src + off + 4);
    v8bf o;
    o[0]=(bf16_t)a.x; o[1]=(bf16_t)a.y; o[2]=(bf16_t)a.z; o[3]=(bf16_t)a.w;
    o[4]=(bf16_t)b.x; o[5]=(bf16_t)b.y; o[6]=(bf16_t)b.z; o[7]=(bf16_t)b.w;
    *(v8bf*)(dst + off) = o;
}

// ---------------------------------------------------------------------------
// Kernel 1: QKV = h @ [wq|wk|wv]^T, fused RoPE on Q,K. Double-buffered K-loop,
// rotation-recurrence RoPE epilogue. Q,K: [32][2048][64]; V^T: [32][64][2048].
// ---------------------------------------------------------------------------
__global__ __launch_bounds__(256) void qkv_gemm_rope(
    const bf16_t* __restrict__ A,   // h bf16 [4096][1024]
    const bf16_t* __restrict__ wq,
    const bf16_t* __restrict__ wk,
    const bf16_t* __restrict__ wv,
    bf16_t* __restrict__ qo, bf16_t* __restrict__ ko, bf16_t* __restrict__ vo)
{
    __shared__ __align__(16) bf16_t smem[17408];

    const int tid = threadIdx.x;
    const int n0  = blockIdx.x * 128;
    const int m0  = blockIdx.y * 128;
    const int sel = n0 >> 10;               // 0=Q 1=K 2=V
    const bf16_t* W = (sel == 0) ? wq : (sel == 1) ? wk : wv;
    const int wr0 = n0 & 1023;

    const int wave = tid >> 6;
    const int lane = tid & 63;
    const int l16  = lane & 15;
    const int quad = lane >> 4;
    const int wrow = (wave >> 1) * 64;
    const int wcol = (wave & 1) * 64;

    v4f acc[4][4];
    #pragma unroll
    for (int i = 0; i < 4; ++i)
        #pragma unroll
        for (int j = 0; j < 4; ++j) acc[i][j] = (v4f)(0.0f);

    const int c0r  = tid >> 2;
    const int c0c  = (tid & 3) * 8;
    #define QKV_STAGE(bbuf, ktile)                                             \
        {                                                                      \
            const int k0_ = (ktile) * 32;                                      \
            load_lds16(A + (size_t)(m0 + c0r) * 1024 + k0_ + c0c,              \
                       smem + (bbuf) * 4096 + tid * 8);                        \
            load_lds16(A + (size_t)(m0 + 64 + c0r) * 1024 + k0_ + c0c,         \
                       smem + (bbuf) * 4096 + 2048 + tid * 8);                 \
            load_lds16(W + (size_t)(wr0 + c0r) * 1024 + k0_ + c0c,             \
                       smem + 8192 + (bbuf) * 4096 + tid * 8);                 \
            load_lds16(W + (size_t)(wr0 + 64 + c0r) * 1024 + k0_ + c0c,        \
                       smem + 8192 + (bbuf) * 4096 + 2048 + tid * 8);          \
        }

    QKV_STAGE(0, 0);
    for (int kt = 0; kt < 32; ++kt) {
        const int cur = kt & 1;
        __syncthreads();
        if (kt < 31) QKV_STAGE(cur ^ 1, kt + 1);

        const bf16_t* As = smem + cur * 4096;
        const bf16_t* Bs = smem + 8192 + cur * 4096;
        v8bf af[4], bfb[4];
        #pragma unroll
        for (int i = 0; i < 4; ++i) {
            af[i]  = *(const v8bf*)&As[(wrow + i * 16 + l16) * 32 + quad * 8];
            bfb[i] = *(const v8bf*)&Bs[(wcol + i * 16 + l16) * 32 + quad * 8];
        }
        #pragma unroll
        for (int i = 0; i < 4; ++i)
            #pragma unroll
            for (int j = 0; j < 4; ++j)
                acc[i][j] = __builtin_amdgcn_mfma_f32_16x16x32_bf16(
                    af[i], bfb[j], acc[i][j], 0, 0, 0);
    }
    __syncthreads();
    #undef QKV_STAGE

    bf16_t* Ls = smem + wave * 4352;          // [64][stride 68]
    const int bq     = (m0 + wrow) >> 11;
    const int hd     = ((n0 + wcol) >> 6) & 15;
    const int t_base = (m0 + wrow) & 2047;

    if (sel < 2) {
        bf16_t* OUT = (sel == 0) ? qo : ko;
        #pragma unroll
        for (int j = 0; j < 4; ++j) {
            const int dcol = j * 16 + l16;
            const int kk   = dcol >> 1;
            const float f  = exp2f((float)kk * -0.4152410118609203f);
            float cb, sb, c1, s1, c16, s16;
            fast_sincos((float)(t_base + quad * 4) * f, &sb, &cb);
            fast_sincos(f, &s1, &c1);
            fast_sincos(16.0f * f, &s16, &c16);
            float ci = cb, si = sb;
            #pragma unroll
            for (int i = 0; i < 4; ++i) {
                float cr = ci, sr = si;
                #pragma unroll
                for (int r = 0; r < 4; ++r) {
                    const int mrow = i * 16 + quad * 4 + r;
                    float v = acc[i][j][r];
                    const float vp = __shfl_xor(v, 1);   // pair d^1 = lane^1
                    v = ((dcol & 1) == 0) ? (cr * v - sr * vp)
                                          : (sr * vp + cr * v);
                    Ls[mrow * 68 + dcol] = (bf16_t)v;
                    if (r < 3) {
                        const float cn = cr * c1 - sr * s1;
                        sr = sr * c1 + cr * s1;
                        cr = cn;
                    }
                }
                if (i < 3) {
                    const float cn = ci * c16 - si * s16;
                    si = si * c16 + ci * s16;
                    ci = cn;
                }
            }
        }
        #pragma unroll
        for (int s = 0; s < 8; ++s) {
            const int row = s * 8 + (lane >> 3);
            const int off = (lane & 7) * 8;
            const v8bf vv = *(const v8bf*)&Ls[row * 68 + off];
            *(v8bf*)(OUT + (((size_t)(bq * 16 + hd) * 2048) + t_base + row) * 64 + off) = vv;
        }
    } else {
        #pragma unroll
        for (int i = 0; i < 4; ++i)
            #pragma unroll
            for (int j = 0; j < 4; ++j) {
                v4bf p;
                #pragma unroll
                for (int r = 0; r < 4; ++r) p[r] = (bf16_t)acc[i][j][r];
                *(v4bf*)&Ls[(j * 16 + l16) * 68 + i * 16 + quad * 4] = p;
            }
        #pragma unroll
        for (int s = 0; s < 8; ++s) {
            const int drow = s * 8 + (lane >> 3);
            const int off  = (lane & 7) * 8;
            const v8bf vv = *(const v8bf*)&Ls[drow * 68 + off];
            *(v8bf*)(vo + (((size_t)(bq * 16 + hd) * 64) + drow) * 2048 + t_base + off) = vv;
        }
    }
}

// ---------------------------------------------------------------------------
// Kernel 2: causal flash attention — round-3 loop structure (proven 52.8us)
// with WAVE-PAIR K-SPLIT (round 6):
//  * pair p = wave>>1 owns 32 q-rows (2 groups of 16); wave h = wave&1
//    processes k-half h of every 64-key tile with its own running (m,l,O)
//    (flash over disjoint key subsets is exact); merged once at the end.
//  * per wave-tile: 4 K-frag + 4 V-frag + 2 P-frag b128 reads for 18 MFMAs
//    (each K/V frag feeds 2 MFMAs via the 2 q-groups) vs 18 reads/18 MFMAs
//    before -> per-CU LDS read traffic -44% at UNCHANGED occupancy
//    (16 waves/CU, 4 blocks/CU, 40KB LDS, same barrier structure).
//  * only all-masked wave-tile is (pair0, h1, diagonal) — wave-uniform skip.
//  * end merge: m*=max, a=exp2(m-m*), l*=sum(l*a), O*=sum(O*a); exp2(-inf)=0
//    makes the never-ran partner (q64==0 edge) combine correctly.
// ---------------------------------------------------------------------------
__global__ __launch_bounds__(256, 4) void attn_mfma(
    const bf16_t* __restrict__ qg,
    const bf16_t* __restrict__ kg,
    const bf16_t* __restrict__ vtg,
    bf16_t* __restrict__ og)
{
    __shared__ __align__(16) bf16_t Ks[2][4096];   // [64 k][64 d] swizzled, dbuf
    __shared__ __align__(16) bf16_t Vs[2][4096];   // [64 d][64 k] swizzled, dbuf
    __shared__ __align__(16) bf16_t Ps[8][512];    // [wave*2+qc][16 q][32 k], 64B rows

    const int tid  = threadIdx.x;          // 0..255
    const int wave = tid >> 6;             // 0..3
    const int lane = tid & 63;
    const int l16  = lane & 15;
    const int quad = lane >> 4;
    const int pr   = wave >> 1;            // pair 0/1 (q-rows)
    const int hf   = wave & 1;             // k-half 0/1

    const int i   = blockIdx.x;            // 0..1023
    const int xcd = i & 7;
    const int j   = i >> 3;                // 0..127
    const int bhl = j >> 5;                // 0..3
    const int u   = j & 31;
    const int q64 = (bhl & 1) ? (31 - u) : u;
    const int bh  = xcd * 4 + bhl;
    const int b = bh >> 4, hh = bh & 15;

    const char* Kb = (const char*)(kg  + (size_t)bh * 2048 * 64);
    const char* Vb = (const char*)(vtg + (size_t)bh * 64 * 2048);

    const int q0 = q64 * 64 + pr * 32;     // pair's first q row

    const int sw  = (l16 & 7) << 4;        // XOR swizzle for 128B rows
    const int sw4 = (l16 & 3) << 4;        // XOR swizzle for 64B P rows
    const int cb0 = (quad << 4) ^ sw;      // K frag read col byte (d-half 0)
    const int vb0 = ((hf << 6) | (quad << 4)) ^ sw;  // V frag read (k-half hf)

    const int grow = tid >> 3;                               // 0..31
    const int gsw  = ((tid & 7) << 4) ^ ((grow & 7) << 4);   // swizzled col byte

    // Q B-frags, 2 q-groups; fold 1/8 * log2(e) (softmax runs in exp2 domain)
    v8bf qf[2][2];
    #pragma unroll
    for (int qc = 0; qc < 2; ++qc) {
        const bf16_t* qrow = qg + ((size_t)bh * 2048 + q0 + qc * 16 + l16) * 64;
        qf[qc][0] = *(const v8bf*)(qrow + quad * 8);
        qf[qc][1] = *(const v8bf*)(qrow + 32 + quad * 8);
        #pragma unroll
        for (int e = 0; e < 8; ++e) {
            qf[qc][0][e] = (bf16_t)((float)qf[qc][0][e] * 0.18033688011112042f);
            qf[qc][1][e] = (bf16_t)((float)qf[qc][1][e] * 0.18033688011112042f);
        }
    }

    v8bf ones1;
    #pragma unroll
    for (int e = 0; e < 8; ++e) ones1[e] = (bf16_t)1.0f;

    float m_r[2] = {-1e30f, -1e30f};
    v4f l_acc[2];
    l_acc[0] = (v4f)(0.0f); l_acc[1] = (v4f)(0.0f);
    v4f o_acc[2][4];
    #pragma unroll
    for (int qc = 0; qc < 2; ++qc)
        #pragma unroll
        for (int d = 0; d < 4; ++d) o_acc[qc][d] = (v4f)(0.0f);

    // stage tile 0 into buffer 0 (async; first barrier drains vmcnt)
    {
        const char* ks = Kb + ((size_t)grow << 7) + gsw;
        const char* vs = Vb + ((size_t)grow << 12) + gsw;
        char* kd = (char*)Ks[0] + tid * 16;
        char* vd = (char*)Vs[0] + tid * 16;
        load_lds16b(ks, kd);
        load_lds16b(ks + (32 << 7), kd + 4096);
        load_lds16b(vs, vd);
        load_lds16b(vs + ((size_t)32 << 12), vd + 4096);
    }

    for (int kt = 0; kt <= q64; ++kt) {
        const int cur = kt & 1;
        const int nxt = cur ^ 1;
        __syncthreads();   // buf[cur] loads drained; prior reads of buf[nxt] done

        // issue async prefetch of tile kt+1 into buf[nxt] (completes under MFMA)
        if (kt < q64) {
            const char* ks = Kb + ((size_t)((kt + 1) * 64 + grow) << 7) + gsw;
            const char* vs = Vb + ((size_t)grow << 12) + ((size_t)(kt + 1) << 7) + gsw;
            char* kd = (char*)Ks[nxt] + tid * 16;
            char* vd = (char*)Vs[nxt] + tid * 16;
            load_lds16b(ks, kd);
            load_lds16b(ks + (32 << 7), kd + 4096);
            load_lds16b(vs, vd);
            load_lds16b(vs + ((size_t)32 << 12), vd + 4096);
        }

        // only all-masked case: pair0's upper k-half on the diagonal tile
        const bool active = !(pr == 0 && hf == 1 && kt == q64);
        if (active) {
            // ---- S^T for this wave's 32-key half, both q-groups ----
            const char* ksc = (const char*)Ks[cur];
            v4f s_acc[2][2];   // [qc][kb2]
            s_acc[0][0] = (v4f)(0.0f); s_acc[0][1] = (v4f)(0.0f);
            s_acc[1][0] = (v4f)(0.0f); s_acc[1][1] = (v4f)(0.0f);
            #pragma unroll
            for (int kb2 = 0; kb2 < 2; ++kb2) {
                const char* kr = ksc + (((hf * 2 + kb2) * 16 + l16) << 7);
                const v8bf kf0 = *(const v8bf*)(kr + cb0);
                const v8bf kf1 = *(const v8bf*)(kr + (cb0 ^ 64));
                s_acc[0][kb2] = __builtin_amdgcn_mfma_f32_16x16x32_bf16(
                    kf0, qf[0][0], s_acc[0][kb2], 0, 0, 0);
                s_acc[1][kb2] = __builtin_amdgcn_mfma_f32_16x16x32_bf16(
                    kf0, qf[1][0], s_acc[1][kb2], 0, 0, 0);
                s_acc[0][kb2] = __builtin_amdgcn_mfma_f32_16x16x32_bf16(
                    kf1, qf[0][1], s_acc[0][kb2], 0, 0, 0);
                s_acc[1][kb2] = __builtin_amdgcn_mfma_f32_16x16x32_bf16(
                    kf1, qf[1][1], s_acc[1][kb2], 0, 0, 0);
            }

            if (kt == q64) {   // causal mask only on the diagonal tile
                #pragma unroll
                for (int qc = 0; qc < 2; ++qc)
                    #pragma unroll
                    for (int kb2 = 0; kb2 < 2; ++kb2)
                        #pragma unroll
                        for (int r = 0; r < 4; ++r)
                            if (kt * 64 + (hf * 2 + kb2) * 16 + quad * 4 + r >
                                q0 + qc * 16 + l16)
                                s_acc[qc][kb2][r] = -1e30f;
            }

            // ---- online softmax per q-group (exp2 domain, defer-max) ----
            v8bf pf[2];
            #pragma unroll
            for (int qc = 0; qc < 2; ++qc) {
                float mx = fmaxf(
                    fmaxf(fmaxf(s_acc[qc][0][0], s_acc[qc][0][1]),
                          fmaxf(s_acc[qc][0][2], s_acc[qc][0][3])),
                    fmaxf(fmaxf(s_acc[qc][1][0], s_acc[qc][1][1]),
                          fmaxf(s_acc[qc][1][2], s_acc[qc][1][3])));
                mx = fmaxf(mx, __shfl_xor(mx, 16));
                mx = fmaxf(mx, __shfl_xor(mx, 32));
                if (!__all(mx - m_r[qc] <= 8.0f)) {
                    const float mn = fmaxf(m_r[qc], mx);
                    const float a  = exp2f(m_r[qc] - mn);
                    m_r[qc] = mn;
                    l_acc[qc] *= a;
                    #pragma unroll
                    for (int d = 0; d < 4; ++d) o_acc[qc][d] *= a;
                }
                char* psc = (char*)Ps[wave * 2 + qc] + (l16 << 6);
                #pragma unroll
                for (int kb2 = 0; kb2 < 2; ++kb2) {
                    v4bf p;
                    #pragma unroll
                    for (int r = 0; r < 4; ++r)
                        p[r] = (bf16_t)exp2f(s_acc[qc][kb2][r] - m_r[qc]);
                    *(v4bf*)(psc + ((kb2 * 32 + quad * 8) ^ sw4)) = p;
                }
                pf[qc] = *(const v8bf*)(psc + ((quad << 4) ^ sw4));
            }

            // ---- O^T += V^T P^T (V-frags shared by both q-groups) ----
            const char* vsc = (const char*)Vs[cur];
            #pragma unroll
            for (int dblk = 0; dblk < 4; ++dblk) {
                const char* vr = vsc + ((dblk * 16 + l16) << 7);
                const v8bf vf = *(const v8bf*)(vr + vb0);
                o_acc[0][dblk] = __builtin_amdgcn_mfma_f32_16x16x32_bf16(
                    vf, pf[0], o_acc[0][dblk], 0, 0, 0);
                o_acc[1][dblk] = __builtin_amdgcn_mfma_f32_16x16x32_bf16(
                    vf, pf[1], o_acc[1][dblk], 0, 0, 0);
            }
            l_acc[0] = __builtin_amdgcn_mfma_f32_16x16x32_bf16(
                ones1, pf[0], l_acc[0], 0, 0, 0);
            l_acc[1] = __builtin_amdgcn_mfma_f32_16x16x32_bf16(
                ones1, pf[1], l_acc[1], 0, 0, 0);
        }
    }

    // ---- pair merge via LDS scratch (K/V buffers dead after last tile) ----
    __syncthreads();
    float* OF = (float*)Ks;                        // [2 pr][64 lane][32] = 16KB
    float* MF = (float*)Vs;                        // [2 pr][64 lane][4]  = 2KB
    if (hf == 1) {
        float* o = OF + (pr * 64 + lane) * 32;
        #pragma unroll
        for (int qc = 0; qc < 2; ++qc)
            #pragma unroll
            for (int d = 0; d < 4; ++d)
                *(v4f*)(o + qc * 16 + d * 4) = o_acc[qc][d];
        float* ml = MF + (pr * 64 + lane) * 4;
        ml[0] = m_r[0]; ml[1] = l_acc[0][0];
        ml[2] = m_r[1]; ml[3] = l_acc[1][0];
    }
    __syncthreads();
    if (hf == 0) {
        const float* o  = OF + (pr * 64 + lane) * 32;
        const float* ml = MF + (pr * 64 + lane) * 4;
        #pragma unroll
        for (int qc = 0; qc < 2; ++qc) {
            const float m1 = ml[qc * 2], l1 = ml[qc * 2 + 1];
            const float ms = fmaxf(m_r[qc], m1);
            const float a0 = exp2f(m_r[qc] - ms);
            const float a1 = exp2f(m1 - ms);
            const float li = 1.0f / (l_acc[qc][0] * a0 + l1 * a1);
            const size_t base =
                ((size_t)b * 2048 + q0 + qc * 16 + l16) * 1024 + hh * 64;
            #pragma unroll
            for (int d = 0; d < 4; ++d) {
                const v4f o1 = *(const v4f*)(o + qc * 16 + d * 4);
                v4bf ob;
                #pragma unroll
                for (int r = 0; r < 4; ++r)
                    ob[r] = (bf16_t)((o_acc[qc][d][r] * a0 + o1[r] * a1) * li);
                *(v4bf*)(og + base + d * 16 + quad * 4) = ob;
            }
        }
    }
}

// ---------------------------------------------------------------------------
// Kernel 3: d_out(fp32) = og @ wo^T. 128x64 tiles, double-buffered K-loop.
// ---------------------------------------------------------------------------
__global__ __launch_bounds__(256) void out_gemm(
    const bf16_t* __restrict__ A,   // og [4096][1024] bf16
    const bf16_t* __restrict__ W,   // wob [1024][1024] bf16
    float* __restrict__ C)
{
    __shared__ __align__(16) float smemf[6144];   // 24KB
    bf16_t* Sb = (bf16_t*)smemf;

    const int tid = threadIdx.x;
    const int n0  = blockIdx.x * 64;
    const int m0  = blockIdx.y * 128;

    const int wave = tid >> 6;
    const int lane = tid & 63;
    const int l16  = lane & 15;
    const int quad = lane >> 4;
    const int wrow = (wave >> 1) * 64;
    const int wcol = (wave & 1) * 32;

    v4f acc[4][2];
    #pragma unroll
    for (int i = 0; i < 4; ++i)
        #pragma unroll
        for (int j = 0; j < 2; ++j) acc[i][j] = (v4f)(0.0f);

    const int c0r = tid >> 2;
    const int c0c = (tid & 3) * 8;
    #define OUT_STAGE(bbuf, ktile)                                             \
        {                                                                      \
            const int k0_ = (ktile) * 32;                                      \
            load_lds16(A + (size_t)(m0 + c0r) * 1024 + k0_ + c0c,              \
                       Sb + (bbuf) * 4096 + tid * 8);                          \
            load_lds16(A + (size_t)(m0 + 64 + c0r) * 1024 + k0_ + c0c,         \
                       Sb + (bbuf) * 4096 + 2048 + tid * 8);                   \
            load_lds16(W + (size_t)(n0 + (tid >> 2)) * 1024 + k0_ + c0c,       \
                       Sb + 8192 + (bbuf) * 2048 + tid * 8);                   \
        }

    OUT_STAGE(0, 0);
    for (int kt = 0; kt < 32; ++kt) {
        const int cur = kt & 1;
        __syncthreads();
        if (kt < 31) OUT_STAGE(cur ^ 1, kt + 1);

        const bf16_t* As = Sb + cur * 4096;
        const bf16_t* Bs = Sb + 8192 + cur * 2048;
        v8bf af[4], bfb[2];
        #pragma unroll
        for (int i = 0; i < 4; ++i)
            af[i]  = *(const v8bf*)&As[(wrow + i * 16 + l16) * 32 + quad * 8];
        #pragma unroll
        for (int j = 0; j < 2; ++j)
            bfb[j] = *(const v8bf*)&Bs[(wcol + j * 16 + l16) * 32 + quad * 8];
        #pragma unroll
        for (int i = 0; i < 4; ++i)
            #pragma unroll
            for (int j = 0; j < 2; ++j)
                acc[i][j] = __builtin_amdgcn_mfma_f32_16x16x32_bf16(
                    af[i], bfb[j], acc[i][j], 0, 0, 0);
    }
    __syncthreads();
    #undef OUT_STAGE

    float* Lw = smemf + wave * 1088;
    #pragma unroll
    for (int half = 0; half < 2; ++half) {
        #pragma unroll
        for (int ii = 0; ii < 2; ++ii) {
            const int i = half * 2 + ii;
            #pragma unroll
            for (int j = 0; j < 2; ++j)
                #pragma unroll
                for (int r = 0; r < 4; ++r)
                    Lw[(ii * 16 + quad * 4 + r) * 34 + j * 16 + l16] = acc[i][j][r];
        }
        // same-wave LDS RAW: DS pipe in-order per wave
        #pragma unroll
        for (int s = 0; s < 8; ++s) {
            const int row = s * 4 + (lane >> 4);      // 0..31
            const float2 vv = *(const float2*)&Lw[row * 34 + l16 * 2];
            *(float2*)(C + (size_t)(m0 + wrow + half * 32 + row) * 1024
                         + n0 + wcol + l16 * 2) = vv;
        }
    }
}

// ---------------------------------------------------------------------------
extern "C" void kernel_launch(void* const* d_in, const int* in_sizes, int n_in,
                              void* d_out, int out_size, void* d_ws, size_t ws_size,
                              hipStream_t stream) {
    const float* h  = (const float*)d_in[0];
    const float* wq = (const float*)d_in[1];
    const float* wk = (const float*)d_in[2];
    const float* wv = (const float*)d_in[3];
    const float* wo = (const float*)d_in[4];

    const size_t NH = (size_t)4096 * 1024;   // 4M
    const size_t NW = (size_t)1024 * 1024;   // 1M

    bf16_t* hb  = (bf16_t*)d_ws;
    bf16_t* wqb = hb  + NH;
    bf16_t* wkb = wqb + NW;
    bf16_t* wvb = wkb + NW;
    bf16_t* wob = wvb + NW;
    bf16_t* qw  = wob + NW;                  // [32][2048][64]
    bf16_t* kw  = qw + NH;
    bf16_t* vw  = kw + NH;                   // [32][64][2048] (V^T)
    bf16_t* og  = hb;                        // alias: hb dead after qkv
    // total: 20M elems = 40 MB

    cvt_fp32_bf16<<<dim3(4096), dim3(256), 0, stream>>>(
        h, wq, wk, wv, wo, hb, wqb, wkb, wvb, wob);
    qkv_gemm_rope<<<dim3(24, 32), dim3(256), 0, stream>>>(
        hb, wqb, wkb, wvb, qw, kw, vw);
    attn_mfma<<<dim3(1024), dim3(256), 0, stream>>>(qw, kw, vw, og);
    out_gemm<<<dim3(16, 32), dim3(256), 0, stream>>>(og, wob, (float*)d_out);
}

// Round 7
// 185.936 us; speedup vs baseline: 1.0252x; 1.0252x over previous
//
#include <hip/hip_runtime.h>
#include <math.h>

typedef __bf16 bf16_t;
typedef __bf16 v8bf __attribute__((ext_vector_type(8)));
typedef __bf16 v4bf __attribute__((ext_vector_type(4)));
typedef float  v4f  __attribute__((ext_vector_type(4)));

#define AS1 __attribute__((address_space(1)))
#define AS3 __attribute__((address_space(3)))

// async global->LDS 16B copy; LDS dest = wave-uniform base + lane*16
static __device__ __forceinline__ void load_lds16(const bf16_t* g, bf16_t* l) {
    __builtin_amdgcn_global_load_lds((AS1 void*)const_cast<bf16_t*>(g),
                                     (AS3 void*)l, 16, 0, 0);
}
static __device__ __forceinline__ void load_lds16b(const char* g, char* l) {
    __builtin_amdgcn_global_load_lds((AS1 void*)const_cast<char*>(g),
                                     (AS3 void*)l, 16, 0, 0);
}

// sin/cos via native HW ops with explicit revolution reduction (no libcall)
static __device__ __forceinline__ void fast_sincos(float ang, float* sn, float* cs) {
    float rv = ang * 0.15915494309189535f;
    rv -= floorf(rv);
    const float a = rv * 6.283185307179586f;
    *sn = __sinf(a);
    *cs = __cosf(a);
}

// ---------------------------------------------------------------------------
// Kernel 0: fp32 -> bf16 for h + 4 weights. 8M elems, 8/thread.
// ---------------------------------------------------------------------------
__global__ __launch_bounds__(256) void cvt_fp32_bf16(
    const float* __restrict__ h,  const float* __restrict__ wq,
    const float* __restrict__ wk, const float* __restrict__ wv,
    const float* __restrict__ wo,
    bf16_t* __restrict__ hb,  bf16_t* __restrict__ wqb,
    bf16_t* __restrict__ wkb, bf16_t* __restrict__ wvb,
    bf16_t* __restrict__ wob)
{
    const size_t HM = (size_t)4 << 20;
    const size_t i8 = ((size_t)blockIdx.x * 256 + threadIdx.x) * 8;
    const float* src; bf16_t* dst; size_t off;
    if (i8 < HM) { src = h; dst = hb; off = i8; }
    else {
        const size_t r = (i8 - HM) >> 20;
        off = (i8 - HM) & (((size_t)1 << 20) - 1);
        src = (r == 0) ? wq  : (r == 1) ? wk  : (r == 2) ? wv  : wo;
        dst = (r == 0) ? wqb : (r == 1) ? wkb : (r == 2) ? wvb : wob;
    }
    const float4 a = *(const float4*)(src + off);
    const float4 b = *(const float4*)(src + off + 4);
    v8bf o;
    o[0]=(bf16_t)a.x; o[1]=(bf16_t)a.y; o[2]=(bf16_t)a.z; o[3]=(bf16_t)a.w;
    o[4]=(bf16_t)b.x; o[5]=(bf16_t)b.y; o[6]=(bf16_t)b.z; o[7]=(bf16_t)b.w;
    *(v8bf*)(dst + off) = o;
}

// ---------------------------------------------------------------------------
// Kernel 1: QKV = h @ [wq|wk|wv]^T, fused RoPE on Q,K. Double-buffered K-loop,
// rotation-recurrence RoPE epilogue. Q,K: [32][2048][64]; V^T: [32][64][2048].
// ---------------------------------------------------------------------------
__global__ __launch_bounds__(256) void qkv_gemm_rope(
    const bf16_t* __restrict__ A,   // h bf16 [4096][1024]
    const bf16_t* __restrict__ wq,
    const bf16_t* __restrict__ wk,
    const bf16_t* __restrict__ wv,
    bf16_t* __restrict__ qo, bf16_t* __restrict__ ko, bf16_t* __restrict__ vo)
{
    __shared__ __align__(16) bf16_t smem[17408];

    const int tid = threadIdx.x;
    const int n0  = blockIdx.x * 128;
    const int m0  = blockIdx.y * 128;
    const int sel = n0 >> 10;               // 0=Q 1=K 2=V
    const bf16_t* W = (sel == 0) ? wq : (sel == 1) ? wk : wv;
    const int wr0 = n0 & 1023;

    const int wave = tid >> 6;
    const int lane = tid & 63;
    const int l16  = lane & 15;
    const int quad = lane >> 4;
    const int wrow = (wave >> 1) * 64;
    const int wcol = (wave & 1) * 64;

    v4f acc[4][4];
    #pragma unroll
    for (int i = 0; i < 4; ++i)
        #pragma unroll
        for (int j = 0; j < 4; ++j) acc[i][j] = (v4f)(0.0f);

    const int c0r  = tid >> 2;
    const int c0c  = (tid & 3) * 8;
    #define QKV_STAGE(bbuf, ktile)                                             \
        {                                                                      \
            const int k0_ = (ktile) * 32;                                      \
            load_lds16(A + (size_t)(m0 + c0r) * 1024 + k0_ + c0c,              \
                       smem + (bbuf) * 4096 + tid * 8);                        \
            load_lds16(A + (size_t)(m0 + 64 + c0r) * 1024 + k0_ + c0c,         \
                       smem + (bbuf) * 4096 + 2048 + tid * 8);                 \
            load_lds16(W + (size_t)(wr0 + c0r) * 1024 + k0_ + c0c,             \
                       smem + 8192 + (bbuf) * 4096 + tid * 8);                 \
            load_lds16(W + (size_t)(wr0 + 64 + c0r) * 1024 + k0_ + c0c,        \
                       smem + 8192 + (bbuf) * 4096 + 2048 + tid * 8);          \
        }

    QKV_STAGE(0, 0);
    for (int kt = 0; kt < 32; ++kt) {
        const int cur = kt & 1;
        __syncthreads();
        if (kt < 31) QKV_STAGE(cur ^ 1, kt + 1);

        const bf16_t* As = smem + cur * 4096;
        const bf16_t* Bs = smem + 8192 + cur * 4096;
        v8bf af[4], bfb[4];
        #pragma unroll
        for (int i = 0; i < 4; ++i) {
            af[i]  = *(const v8bf*)&As[(wrow + i * 16 + l16) * 32 + quad * 8];
            bfb[i] = *(const v8bf*)&Bs[(wcol + i * 16 + l16) * 32 + quad * 8];
        }
        #pragma unroll
        for (int i = 0; i < 4; ++i)
            #pragma unroll
            for (int j = 0; j < 4; ++j)
                acc[i][j] = __builtin_amdgcn_mfma_f32_16x16x32_bf16(
                    af[i], bfb[j], acc[i][j], 0, 0, 0);
    }
    __syncthreads();
    #undef QKV_STAGE

    bf16_t* Ls = smem + wave * 4352;          // [64][stride 68]
    const int bq     = (m0 + wrow) >> 11;
    const int hd     = ((n0 + wcol) >> 6) & 15;
    const int t_base = (m0 + wrow) & 2047;

    if (sel < 2) {
        bf16_t* OUT = (sel == 0) ? qo : ko;
        #pragma unroll
        for (int j = 0; j < 4; ++j) {
            const int dcol = j * 16 + l16;
            const int kk   = dcol >> 1;
            const float f  = exp2f((float)kk * -0.4152410118609203f);
            float cb, sb, c1, s1, c16, s16;
            fast_sincos((float)(t_base + quad * 4) * f, &sb, &cb);
            fast_sincos(f, &s1, &c1);
            fast_sincos(16.0f * f, &s16, &c16);
            float ci = cb, si = sb;
            #pragma unroll
            for (int i = 0; i < 4; ++i) {
                float cr = ci, sr = si;
                #pragma unroll
                for (int r = 0; r < 4; ++r) {
                    const int mrow = i * 16 + quad * 4 + r;
                    float v = acc[i][j][r];
                    const float vp = __shfl_xor(v, 1);   // pair d^1 = lane^1
                    v = ((dcol & 1) == 0) ? (cr * v - sr * vp)
                                          : (sr * vp + cr * v);
                    Ls[mrow * 68 + dcol] = (bf16_t)v;
                    if (r < 3) {
                        const float cn = cr * c1 - sr * s1;
                        sr = sr * c1 + cr * s1;
                        cr = cn;
                    }
                }
                if (i < 3) {
                    const float cn = ci * c16 - si * s16;
                    si = si * c16 + ci * s16;
                    ci = cn;
                }
            }
        }
        #pragma unroll
        for (int s = 0; s < 8; ++s) {
            const int row = s * 8 + (lane >> 3);
            const int off = (lane & 7) * 8;
            const v8bf vv = *(const v8bf*)&Ls[row * 68 + off];
            *(v8bf*)(OUT + (((size_t)(bq * 16 + hd) * 2048) + t_base + row) * 64 + off) = vv;
        }
    } else {
        #pragma unroll
        for (int i = 0; i < 4; ++i)
            #pragma unroll
            for (int j = 0; j < 4; ++j) {
                v4bf p;
                #pragma unroll
                for (int r = 0; r < 4; ++r) p[r] = (bf16_t)acc[i][j][r];
                *(v4bf*)&Ls[(j * 16 + l16) * 68 + i * 16 + quad * 4] = p;
            }
        #pragma unroll
        for (int s = 0; s < 8; ++s) {
            const int drow = s * 8 + (lane >> 3);
            const int off  = (lane & 7) * 8;
            const v8bf vv = *(const v8bf*)&Ls[drow * 68 + off];
            *(v8bf*)(vo + (((size_t)(bq * 16 + hd) * 64) + drow) * 2048 + t_base + off) = vv;
        }
    }
}

// ---------------------------------------------------------------------------
// Kernel 2: causal flash attention — round-2/5 proven geometry (64-key tiles,
// double-buffered K/V, 4 waves x 16 q-rows, grid 1024, 4 blocks/CU) with the
// P LDS ROUND-TRIP ELIMINATED (round 7, T12 analog for 16x16):
//   S^T acc holds P[k=kblk*16+quad*4+r][q=l16]; PV B-frag needs
//   P[k=quad*8+e][q=l16]. In-register redistribution:
//     w[kblk][h] = v_cvt_pk_bf16_f32(exp2 pair)          (8 packs)
//     per (pf-half g, h): permlane32_swap(a=w[2g][h], b=w[2g+1][h])
//       -> a={X.lo,Y.lo}, b={X.hi,Y.hi}; ds_swizzle xor16 of each;
//       frag word j=h   = (lane&16) ? b_swz : a
//       frag word j=2+h = (lane&16) ? b     : a_swz
//   (lane-exact derivation in session notes; replaces 4 ds_write + 2
//   ds_read_b128 + LDS RAW wait per wave-tile; Ps buffer deleted -> 32KB LDS)
// ---------------------------------------------------------------------------
__global__ __launch_bounds__(256, 4) void attn_mfma(
    const bf16_t* __restrict__ qg,
    const bf16_t* __restrict__ kg,
    const bf16_t* __restrict__ vtg,
    bf16_t* __restrict__ og)
{
    __shared__ __align__(16) bf16_t Ks[2][4096];   // [64 k][64 d] swizzled
    __shared__ __align__(16) bf16_t Vs[2][4096];   // [64 d][64 k] swizzled

    const int tid  = threadIdx.x;          // 0..255
    const int wave = tid >> 6;             // 0..3
    const int lane = tid & 63;
    const int l16  = lane & 15;
    const int quad = lane >> 4;

    const int i   = blockIdx.x;            // 0..1023
    const int xcd = i & 7;
    const int j   = i >> 3;                // 0..127
    const int bhl = j >> 5;                // 0..3
    const int u   = j & 31;
    const int q64 = (bhl & 1) ? (31 - u) : u;
    const int bh  = xcd * 4 + bhl;
    const int b = bh >> 4, hh = bh & 15;

    const char* Kb = (const char*)(kg  + (size_t)bh * 2048 * 64);
    const char* Vb = (const char*)(vtg + (size_t)bh * 64 * 2048);

    const int qglb = q64 * 64 + wave * 16 + l16;   // this lane's Q row

    const int sw  = (l16 & 7) << 4;        // XOR swizzle for rows == l16 (mod 8)
    const int cb0 = (quad << 4) ^ sw;      // frag read col byte (first 64B half)

    const int grow = tid >> 3;                               // 0..31
    const int gsw  = ((tid & 7) << 4) ^ ((grow & 7) << 4);   // swizzled col byte

    const bf16_t* qrow = qg + ((size_t)bh * 2048 + qglb) * 64;
    v8bf qf[2];
    qf[0] = *(const v8bf*)(qrow + quad * 8);
    qf[1] = *(const v8bf*)(qrow + 32 + quad * 8);
    #pragma unroll
    for (int e = 0; e < 8; ++e) {
        qf[0][e] = (bf16_t)((float)qf[0][e] * 0.18033688011112042f);
        qf[1][e] = (bf16_t)((float)qf[1][e] * 0.18033688011112042f);
    }

    v8bf ones1;
    #pragma unroll
    for (int e = 0; e < 8; ++e) ones1[e] = (bf16_t)1.0f;

    float m_r = -1e30f;
    v4f l_acc = (v4f)(0.0f);
    v4f o_acc[4];
    #pragma unroll
    for (int d = 0; d < 4; ++d) o_acc[d] = (v4f)(0.0f);

    {
        const char* ks = Kb + ((size_t)grow << 7) + gsw;
        const char* vs = Vb + ((size_t)grow << 12) + gsw;
        char* kd = (char*)Ks[0] + tid * 16;
        char* vd = (char*)Vs[0] + tid * 16;
        load_lds16b(ks, kd);
        load_lds16b(ks + (32 << 7), kd + 4096);
        load_lds16b(vs, vd);
        load_lds16b(vs + ((size_t)32 << 12), vd + 4096);
    }

    for (int kt = 0; kt <= q64; ++kt) {
        const int cur = kt & 1;
        const int nxt = cur ^ 1;
        __syncthreads();   // buf[cur] loads drained; prior reads of buf[nxt] done

        // issue async prefetch of tile kt+1 into buf[nxt] (completes under MFMA)
        if (kt < q64) {
            const char* ks = Kb + ((size_t)((kt + 1) * 64 + grow) << 7) + gsw;
            const char* vs = Vb + ((size_t)grow << 12) + ((size_t)(kt + 1) << 7) + gsw;
            char* kd = (char*)Ks[nxt] + tid * 16;
            char* vd = (char*)Vs[nxt] + tid * 16;
            load_lds16b(ks, kd);
            load_lds16b(ks + (32 << 7), kd + 4096);
            load_lds16b(vs, vd);
            load_lds16b(vs + ((size_t)32 << 12), vd + 4096);
        }

        // ---- S^T tile ----
        const char* ksc = (const char*)Ks[cur];
        v4f s_acc[4];
        #pragma unroll
        for (int kblk = 0; kblk < 4; ++kblk) s_acc[kblk] = (v4f)(0.0f);
        #pragma unroll
        for (int kblk = 0; kblk < 4; ++kblk) {
            const char* kr = ksc + ((kblk * 16 + l16) << 7);
            const v8bf kf0 = *(const v8bf*)(kr + cb0);
            const v8bf kf1 = *(const v8bf*)(kr + (cb0 ^ 64));
            s_acc[kblk] = __builtin_amdgcn_mfma_f32_16x16x32_bf16(
                kf0, qf[0], s_acc[kblk], 0, 0, 0);
            s_acc[kblk] = __builtin_amdgcn_mfma_f32_16x16x32_bf16(
                kf1, qf[1], s_acc[kblk], 0, 0, 0);
        }

        // ---- early V-frag reads (only pre-PV DS now; hide under softmax) ----
        const char* vsc = (const char*)Vs[cur];
        v8bf vfr[4][2];
        #pragma unroll
        for (int dblk = 0; dblk < 4; ++dblk) {
            const char* vr = vsc + ((dblk * 16 + l16) << 7);
            vfr[dblk][0] = *(const v8bf*)(vr + cb0);
            vfr[dblk][1] = *(const v8bf*)(vr + (cb0 ^ 64));
        }

        if (kt == q64) {   // causal mask only on the diagonal (= last) tile
            #pragma unroll
            for (int kblk = 0; kblk < 4; ++kblk)
                #pragma unroll
                for (int r = 0; r < 4; ++r)
                    if (kt * 64 + kblk * 16 + quad * 4 + r > qglb)
                        s_acc[kblk][r] = -1e30f;
        }

        // ---- online softmax max (exp2 domain), defer-max rescale ----
        float m01 = fmaxf(fmaxf(s_acc[0][0], s_acc[0][1]),
                          fmaxf(s_acc[0][2], s_acc[0][3]));
        float m23 = fmaxf(fmaxf(s_acc[1][0], s_acc[1][1]),
                          fmaxf(s_acc[1][2], s_acc[1][3]));
        float m45 = fmaxf(fmaxf(s_acc[2][0], s_acc[2][1]),
                          fmaxf(s_acc[2][2], s_acc[2][3]));
        float m67 = fmaxf(fmaxf(s_acc[3][0], s_acc[3][1]),
                          fmaxf(s_acc[3][2], s_acc[3][3]));
        float mx = fmaxf(fmaxf(m01, m23), fmaxf(m45, m67));
        mx = fmaxf(mx, __shfl_xor(mx, 16));
        mx = fmaxf(mx, __shfl_xor(mx, 32));
        if (!__all(mx - m_r <= 8.0f)) {
            const float mn = fmaxf(m_r, mx);
            const float a  = exp2f(m_r - mn);
            m_r = mn;
            l_acc *= a;
            #pragma unroll
            for (int d = 0; d < 4; ++d) o_acc[d] *= a;
        }

        // ---- exp2 + cvt_pk: w[kblk][h] = pack(P[k=kblk*16+quad*4+2h], +1) ----
        unsigned w[4][2];
        #pragma unroll
        for (int kblk = 0; kblk < 4; ++kblk) {
            #pragma unroll
            for (int h2 = 0; h2 < 2; ++h2) {
                const float e0 = exp2f(s_acc[kblk][2 * h2]     - m_r);
                const float e1 = exp2f(s_acc[kblk][2 * h2 + 1] - m_r);
                asm("v_cvt_pk_bf16_f32 %0, %1, %2"
                    : "=v"(w[kblk][h2]) : "v"(e0), "v"(e1));
            }
        }

        // ---- in-register redistribution -> PV B-frags pf[0] (k 0-31),
        //      pf[1] (k 32-63); no LDS round-trip ----
        union PF { unsigned u[4]; v8bf v; } pf[2];
        #pragma unroll
        for (int g = 0; g < 2; ++g) {
            #pragma unroll
            for (int h2 = 0; h2 < 2; ++h2) {
                unsigned a = w[g * 2][h2];      // X = kblk 2g
                unsigned bb = w[g * 2 + 1][h2]; // Y = kblk 2g+1
                asm("v_permlane32_swap_b32 %0, %1" : "+v"(a), "+v"(bb));
                // a = {X.lo32, Y.lo32}; bb = {X.hi32, Y.hi32}
                const unsigned aswz = __builtin_amdgcn_ds_swizzle(a, 0x401F);
                const unsigned bswz = __builtin_amdgcn_ds_swizzle(bb, 0x401F);
                pf[g].u[h2]     = (lane & 16) ? bswz : a;
                pf[g].u[2 + h2] = (lane & 16) ? bb   : aswz;
            }
        }

        // ---- O^T += V^T P^T; l += ones * P^T (2 extra MFMAs) ----
        #pragma unroll
        for (int dblk = 0; dblk < 4; ++dblk) {
            o_acc[dblk] = __builtin_amdgcn_mfma_f32_16x16x32_bf16(
                vfr[dblk][0], pf[0].v, o_acc[dblk], 0, 0, 0);
            o_acc[dblk] = __builtin_amdgcn_mfma_f32_16x16x32_bf16(
                vfr[dblk][1], pf[1].v, o_acc[dblk], 0, 0, 0);
        }
        l_acc = __builtin_amdgcn_mfma_f32_16x16x32_bf16(
            ones1, pf[0].v, l_acc, 0, 0, 0);
        l_acc = __builtin_amdgcn_mfma_f32_16x16x32_bf16(
            ones1, pf[1].v, l_acc, 0, 0, 0);
    }

    const float inv_l = 1.0f / l_acc[0];
    const size_t base = ((size_t)b * 2048 + qglb) * 1024 + hh * 64;
    #pragma unroll
    for (int dblk = 0; dblk < 4; ++dblk) {
        v4bf o;
        #pragma unroll
        for (int r = 0; r < 4; ++r) o[r] = (bf16_t)(o_acc[dblk][r] * inv_l);
        *(v4bf*)(og + base + dblk * 16 + quad * 4) = o;
    }
}

// ---------------------------------------------------------------------------
// Kernel 3: d_out(fp32) = og @ wo^T. 128x64 tiles, double-buffered K-loop.
// ---------------------------------------------------------------------------
__global__ __launch_bounds__(256) void out_gemm(
    const bf16_t* __restrict__ A,   // og [4096][1024] bf16
    const bf16_t* __restrict__ W,   // wob [1024][1024] bf16
    float* __restrict__ C)
{
    __shared__ __align__(16) float smemf[6144];   // 24KB
    bf16_t* Sb = (bf16_t*)smemf;

    const int tid = threadIdx.x;
    const int n0  = blockIdx.x * 64;
    const int m0  = blockIdx.y * 128;

    const int wave = tid >> 6;
    const int lane = tid & 63;
    const int l16  = lane & 15;
    const int quad = lane >> 4;
    const int wrow = (wave >> 1) * 64;
    const int wcol = (wave & 1) * 32;

    v4f acc[4][2];
    #pragma unroll
    for (int i = 0; i < 4; ++i)
        #pragma unroll
        for (int j = 0; j < 2; ++j) acc[i][j] = (v4f)(0.0f);

    const int c0r = tid >> 2;
    const int c0c = (tid & 3) * 8;
    #define OUT_STAGE(bbuf, ktile)                                             \
        {                                                                      \
            const int k0_ = (ktile) * 32;                                      \
            load_lds16(A + (size_t)(m0 + c0r) * 1024 + k0_ + c0c,              \
                       Sb + (bbuf) * 4096 + tid * 8);                          \
            load_lds16(A + (size_t)(m0 + 64 + c0r) * 1024 + k0_ + c0c,         \
                       Sb + (bbuf) * 4096 + 2048 + tid * 8);                   \
            load_lds16(W + (size_t)(n0 + (tid >> 2)) * 1024 + k0_ + c0c,       \
                       Sb + 8192 + (bbuf) * 2048 + tid * 8);                   \
        }

    OUT_STAGE(0, 0);
    for (int kt = 0; kt < 32; ++kt) {
        const int cur = kt & 1;
        __syncthreads();
        if (kt < 31) OUT_STAGE(cur ^ 1, kt + 1);

        const bf16_t* As = Sb + cur * 4096;
        const bf16_t* Bs = Sb + 8192 + cur * 2048;
        v8bf af[4], bfb[2];
        #pragma unroll
        for (int i = 0; i < 4; ++i)
            af[i]  = *(const v8bf*)&As[(wrow + i * 16 + l16) * 32 + quad * 8];
        #pragma unroll
        for (int j = 0; j < 2; ++j)
            bfb[j] = *(const v8bf*)&Bs[(wcol + j * 16 + l16) * 32 + quad * 8];
        #pragma unroll
        for (int i = 0; i < 4; ++i)
            #pragma unroll
            for (int j = 0; j < 2; ++j)
                acc[i][j] = __builtin_amdgcn_mfma_f32_16x16x32_bf16(
                    af[i], bfb[j], acc[i][j], 0, 0, 0);
    }
    __syncthreads();
    #undef OUT_STAGE

    float* Lw = smemf + wave * 1088;
    #pragma unroll
    for (int half = 0; half < 2; ++half) {
        #pragma unroll
        for (int ii = 0; ii < 2; ++ii) {
            const int i = half * 2 + ii;
            #pragma unroll
            for (int j = 0; j < 2; ++j)
                #pragma unroll
                for (int r = 0; r < 4; ++r)
                    Lw[(ii * 16 + quad * 4 + r) * 34 + j * 16 + l16] = acc[i][j][r];
        }
        // same-wave LDS RAW: DS pipe in-order per wave
        #pragma unroll
        for (int s = 0; s < 8; ++s) {
            const int row = s * 4 + (lane >> 4);      // 0..31
            const float2 vv = *(const float2*)&Lw[row * 34 + l16 * 2];
            *(float2*)(C + (size_t)(m0 + wrow + half * 32 + row) * 1024
                         + n0 + wcol + l16 * 2) = vv;
        }
    }
}

// ---------------------------------------------------------------------------
extern "C" void kernel_launch(void* const* d_in, const int* in_sizes, int n_in,
                              void* d_out, int out_size, void* d_ws, size_t ws_size,
                              hipStream_t stream) {
    const float* h  = (const float*)d_in[0];
    const float* wq = (const float*)d_in[1];
    const float* wk = (const float*)d_in[2];
    const float* wv = (const float*)d_in[3];
    const float* wo = (const float*)d_in[4];

    const size_t NH = (size_t)4096 * 1024;   // 4M
    const size_t NW = (size_t)1024 * 1024;   // 1M

    bf16_t* hb  = (bf16_t*)d_ws;
    bf16_t* wqb = hb  + NH;
    bf16_t* wkb = wqb + NW;
    bf16_t* wvb = wkb + NW;
    bf16_t* wob = wvb + NW;
    bf16_t* qw  = wob + NW;                  // [32][2048][64]
    bf16_t* kw  = qw + NH;
    bf16_t* vw  = kw + NH;                   // [32][64][2048] (V^T)
    bf16_t* og  = hb;                        // alias: hb dead after qkv
    // total: 20M elems = 40 MB

    cvt_fp32_bf16<<<dim3(4096), dim3(256), 0, stream>>>(
        h, wq, wk, wv, wo, hb, wqb, wkb, wvb, wob);
    qkv_gemm_rope<<<dim3(24, 32), dim3(256), 0, stream>>>(
        hb, wqb, wkb, wvb, qw, kw, vw);
    attn_mfma<<<dim3(1024), dim3(256), 0, stream>>>(qw, kw, vw, og);
    out_gemm<<<dim3(16, 32), dim3(256), 0, stream>>>(og, wob, (float*)d_out);
}